// Round 1
// 143.728 us; speedup vs baseline: 1.0885x; 1.0885x over previous
//
#include <hip/hip_runtime.h>
#include <hip/hip_bf16.h>

#define NN 8
#define TT 192
#define HH 1024
#define DD 128
#define TPP 48
#define EE 16384
#define NEDGE (EE + HH)      // 17408
#define BB (NN * TPP)        // 384
#define NOUT (NN * TT * DD)  // 196608

typedef short bf16x8 __attribute__((ext_vector_type(8)));
typedef float f32x4 __attribute__((ext_vector_type(4)));

__device__ __forceinline__ float us2f(unsigned short u) {
  union { unsigned i; float f; } t;
  t.i = ((unsigned)u) << 16;
  return t.f;
}

__device__ __forceinline__ void acc6(float cf, unsigned u0, unsigned u1, unsigned u2,
                                     float& a0, float& a1, float& a2, float& a3,
                                     float& a4, float& a5) {
  union { unsigned i; float f; } lo, hi;
  lo.i = u0 << 16; hi.i = u0 & 0xffff0000u;
  a0 = fmaf(cf, lo.f, a0); a1 = fmaf(cf, hi.f, a1);
  lo.i = u1 << 16; hi.i = u1 & 0xffff0000u;
  a2 = fmaf(cf, lo.f, a2); a3 = fmaf(cf, hi.f, a3);
  lo.i = u2 << 16; hi.i = u2 & 0xffff0000u;
  a4 = fmaf(cf, lo.f, a4); a5 = fmaf(cf, hi.f, a5);
}

// ---------------- setup: deg atomics, inv, twT, zero-fill, x transpose ----------------
// blocks [0,384): 64x64 transpose tiles + small indexed tasks.
// blocks [384,452): CW = Conv@W1 (640 elts) and W2 swizzle (16384 elts) -- depend
// only on inputs, so they run here concurrently instead of a 1-CU k_scan.
__global__ __launch_bounds__(256) void k_setup(
    const int* __restrict__ edges, int* __restrict__ degE,
    const int* __restrict__ node_split, int* __restrict__ inv,
    const float* __restrict__ tw, float* __restrict__ twT,
    float* __restrict__ zbuf,  // fill|cs|QT region, 6144 floats
    const float* __restrict__ x, __hip_bfloat16* __restrict__ Xall,
    const float* __restrict__ tcw, const float* __restrict__ tcb,
    const float* __restrict__ W1, float* __restrict__ CW,
    const float* __restrict__ W2, __hip_bfloat16* __restrict__ w2sw) {
  __shared__ float tile[64][65];
  int tid = threadIdx.x, bid = blockIdx.x;
  if (bid < 384) {
    int i = bid * 256 + tid;
    if (i < EE) atomicAdd(&degE[edges[2 * i + 1]], 1);
    if (i < HH) inv[node_split[i]] = i;
    if (i < 65536) twT[(i & 511) * DD + (i >> 9)] = tw[i];
    if (i < 6144) zbuf[i] = 0.f;

    int tt = bid % 24, st = bid / 24;  // t-tile, s-tile
    int t0 = tt * 64, s0 = st * 64;
    int sl = tid & 63, r4 = tid >> 6;
#pragma unroll 4
    for (int ii = 0; ii < 16; ++ii) {
      int tl = ii * 4 + r4;
      tile[tl][sl] = x[(size_t)(t0 + tl) * HH + s0 + sl];
    }
    __syncthreads();
#pragma unroll 4
    for (int ii = 0; ii < 16; ++ii) {
      int sl2 = ii * 4 + r4;
      Xall[(size_t)(s0 + sl2) * 1536 + t0 + sl] = __float2bfloat16(tile[sl][sl2]);
    }
  } else {
    int ex = (bid - 384) * 256 + tid;
    if (ex < 640) {
      // CW[j][o] = sum_d Conv[j][d] * W1[d][o]
      int j = ex >> 7, o = ex & 127;
      float acc = 0.f;
      if (j < 4)
        for (int d = 0; d < DD; ++d) acc = fmaf(tcw[d * 4 + j], W1[d * DD + o], acc);
      else
        for (int d = 0; d < DD; ++d) acc = fmaf(tcb[d], W1[d * DD + o], acc);
      CW[j * DD + o] = acc;
    }
    int ew = ex - 1024;
    if (ew >= 0 && ew < 16384) {
      // W2 swizzled bf16 [n][k] for k_out MFMA B operand
      int n = ew >> 7, k = ew & 127;
      int dstb = n * 256 + (((k >> 3) ^ (n & 7)) * 16) + (k & 7) * 2;
      w2sw[dstb >> 1] = __float2bfloat16(W2[k * DD + n]);
    }
  }
}

// ---------------- scatter: per-block LDS scan of degE + CSR + cs row-sums + QT ----------------
// Each block redundantly prefix-scans degE (1024 ints) in LDS -- removes the old
// single-block k_scan launch. Block 0 publishes row_ptr for k_spmm.
__global__ __launch_bounds__(256) void k_scatter(
    const int* __restrict__ edges, const int* __restrict__ degE,
    const int* __restrict__ inv, int* __restrict__ fill,
    int* __restrict__ csr_src, float* __restrict__ csr_coef,
    float* __restrict__ csum, float* __restrict__ QT, int* __restrict__ row_ptr) {
  __shared__ int rp[1024];
  __shared__ int wsumS[4];
  int tid = threadIdx.x, lane = tid & 63, wid = tid >> 6;
  int4 d4 = ((const int4*)degE)[tid];
  int l0 = d4.x + 1, l1 = d4.y + 1, l2 = d4.z + 1, l3 = d4.w + 1;
  int lsum = l0 + l1 + l2 + l3;
  int incl = lsum;
#pragma unroll
  for (int off = 1; off < 64; off <<= 1) {
    int u = __shfl_up(incl, off, 64);
    if (lane >= off) incl += u;
  }
  if (lane == 63) wsumS[wid] = incl;
  __syncthreads();
  int base = 0;
  if (wid > 0) base += wsumS[0];
  if (wid > 1) base += wsumS[1];
  if (wid > 2) base += wsumS[2];
  int excl = base + incl - lsum;
  rp[4 * tid] = excl;
  rp[4 * tid + 1] = excl + l0;
  rp[4 * tid + 2] = excl + l0 + l1;
  rp[4 * tid + 3] = excl + l0 + l1 + l2;
  __syncthreads();
  if (blockIdx.x == 0) {
    for (int i = tid; i < 1024; i += 256) row_ptr[i] = rp[i];
    if (tid == 0) row_ptr[1024] = NEDGE;
  }
  int e = blockIdx.x * 256 + tid;
  if (e < NEDGE) {
    int s, dt;
    if (e < EE) { s = edges[2 * e]; dt = edges[2 * e + 1]; }
    else        { s = dt = e - EE; }
    float ds = (float)(degE[s] + 1);
    float dd = (float)(degE[dt] + 1);
    float cf = rsqrtf(ds * dd);
    int pos = atomicAdd(&fill[dt], 1);
    int at = rp[dt] + pos;
    csr_src[at] = s;
    csr_coef[at] = cf;
    atomicAdd(&csum[dt], cf);
    int g = inv[dt] >> 8;
    atomicAdd(&QT[s * 4 + g], cf * (1.0f / 256.0f));
  }
}

// ---------------- SpMM (xbar = Ahat @ Xall) + time embedding, merged ----------------
// Row branch: stage the row's edge list in LDS, then batch 4 edges (12 loads) in
// flight to break the per-edge dependent-load chain.
__global__ __launch_bounds__(256) void k_spmm(
    const int* __restrict__ row_ptr, const int* __restrict__ csr_src,
    const float* __restrict__ csr_coef, const __hip_bfloat16* __restrict__ Xall,
    __hip_bfloat16* __restrict__ xbar,
    const int* __restrict__ xm, const float* __restrict__ hour_emb,
    const float* __restrict__ wday_emb, const float* __restrict__ twT,
    const float* __restrict__ tcb, float* __restrict__ out) {
  __shared__ float sL[2][512];
  __shared__ int sS[256];
  __shared__ float sC[256];
  int tid = threadIdx.x, bid = blockIdx.x;
  if (bid < HH) {
    int h = bid;
    int j0 = row_ptr[h], j1 = row_ptr[h + 1];
    int cnt = j1 - j0;
    int cs = cnt < 256 ? cnt : 256;
    if (tid < cs) { sS[tid] = csr_src[j0 + tid]; sC[tid] = csr_coef[j0 + tid]; }
    __syncthreads();
    float a0 = 0.f, a1 = 0.f, a2 = 0.f, a3 = 0.f, a4 = 0.f, a5 = 0.f;
    int j = 0;
    for (; j + 4 <= cs; j += 4) {
      const unsigned* x0 = (const unsigned*)(Xall + (size_t)sS[j] * 1536);
      const unsigned* x1 = (const unsigned*)(Xall + (size_t)sS[j + 1] * 1536);
      const unsigned* x2 = (const unsigned*)(Xall + (size_t)sS[j + 2] * 1536);
      const unsigned* x3 = (const unsigned*)(Xall + (size_t)sS[j + 3] * 1536);
      unsigned u00 = x0[tid], u01 = x0[tid + 256], u02 = x0[tid + 512];
      unsigned u10 = x1[tid], u11 = x1[tid + 256], u12 = x1[tid + 512];
      unsigned u20 = x2[tid], u21 = x2[tid + 256], u22 = x2[tid + 512];
      unsigned u30 = x3[tid], u31 = x3[tid + 256], u32 = x3[tid + 512];
      float c0 = sC[j], c1 = sC[j + 1], c2 = sC[j + 2], c3 = sC[j + 3];
      acc6(c0, u00, u01, u02, a0, a1, a2, a3, a4, a5);
      acc6(c1, u10, u11, u12, a0, a1, a2, a3, a4, a5);
      acc6(c2, u20, u21, u22, a0, a1, a2, a3, a4, a5);
      acc6(c3, u30, u31, u32, a0, a1, a2, a3, a4, a5);
    }
    for (; j < cs; ++j) {
      const unsigned* xr = (const unsigned*)(Xall + (size_t)sS[j] * 1536);
      unsigned u0 = xr[tid], u1 = xr[tid + 256], u2 = xr[tid + 512];
      acc6(sC[j], u0, u1, u2, a0, a1, a2, a3, a4, a5);
    }
    for (; j < cnt; ++j) {  // safety: degree > 256 (never expected)
      int s = csr_src[j0 + j];
      float cf = csr_coef[j0 + j];
      const unsigned* xr = (const unsigned*)(Xall + (size_t)s * 1536);
      unsigned u0 = xr[tid], u1 = xr[tid + 256], u2 = xr[tid + 512];
      acc6(cf, u0, u1, u2, a0, a1, a2, a3, a4, a5);
    }
    unsigned* xw = (unsigned*)(xbar + (size_t)h * 1536);
    union { __hip_bfloat16 h2[2]; unsigned u; } pk;
    pk.h2[0] = __float2bfloat16(a0); pk.h2[1] = __float2bfloat16(a1);
    xw[tid] = pk.u;
    pk.h2[0] = __float2bfloat16(a2); pk.h2[1] = __float2bfloat16(a3);
    xw[tid + 256] = pk.u;
    pk.h2[0] = __float2bfloat16(a4); pk.h2[1] = __float2bfloat16(a5);
    xw[tid + 512] = pk.u;
  } else {
    int bb = bid - HH;
    int half = tid >> 7, o = tid & 127;
    int b = bb * 2 + half;
    int n = b / TPP, tp = b % TPP;
    for (int k = 0; k < 4; ++k) {
      int t = tp * 4 + k;
      int wd = xm[(n * TT + t) * 2 + 0];
      int hr = xm[(n * TT + t) * 2 + 1];
      sL[half][o * 4 + k] = hour_emb[hr * DD + o] + wday_emb[wd * DD + o];
    }
    __syncthreads();
    float a0 = tcb[o], a1 = 0.f, a2 = 0.f, a3 = 0.f;
    for (int j = 0; j < 512; j += 4) {
      a0 = fmaf(sL[half][j + 0], twT[(j + 0) * DD + o], a0);
      a1 = fmaf(sL[half][j + 1], twT[(j + 1) * DD + o], a1);
      a2 = fmaf(sL[half][j + 2], twT[(j + 2) * DD + o], a2);
      a3 = fmaf(sL[half][j + 3], twT[(j + 3) * DD + o], a3);
    }
    float acc = (a0 + a1) + (a2 + a3);
    size_t base = (size_t)NOUT + ((size_t)n * TT + tp * 4) * DD + o;
    out[base] = acc;
    out[base + DD] = acc;
    out[base + 2 * DD] = acc;
    out[base + 3 * DD] = acc;
  }
}

// ---------------- k_red: y[b,g,o] = sum_h QT[h,g]*relu(xbar5[b,h,:]@CW + b1) ----------------
// 128 threads, 2 outputs o per lane: halves LDS-broadcast return-path cost per FLOP
// (the old 256-thread version was LDS-pipe-bound at ~9cy LDS vs 5cy effective VALU).
__global__ __launch_bounds__(128) void k_red(const __hip_bfloat16* __restrict__ xbar,
                                             const float* __restrict__ csum,
                                             const float* __restrict__ QT,
                                             const float* __restrict__ CW,
                                             const float* __restrict__ b1,
                                             float* __restrict__ ypar) {
  __shared__ float4 xb4[256];
  __shared__ float4 qv[256];
  __shared__ float csv[256];
  __shared__ float yL[512];
  int tid = threadIdx.x, bid = blockIdx.x;
  int b = bid >> 2, qt = bid & 3;
  for (int r = tid; r < 256; r += 128) {
    int h = qt * 256 + r;
    ushort4 us = *(const ushort4*)(xbar + (size_t)h * 1536 + b * 4);
    xb4[r] = make_float4(us2f(us.x), us2f(us.y), us2f(us.z), us2f(us.w));
    qv[r] = *(const float4*)(QT + h * 4);
    csv[r] = csum[h];
  }
  int lane = tid & 63, w = tid >> 6;
  int o0 = lane, o1 = lane + 64;
  float cw0a = CW[o0], cw1a = CW[DD + o0], cw2a = CW[2 * DD + o0];
  float cw3a = CW[3 * DD + o0], cw4a = CW[4 * DD + o0];
  float cw0b = CW[o1], cw1b = CW[DD + o1], cw2b = CW[2 * DD + o1];
  float cw3b = CW[3 * DD + o1], cw4b = CW[4 * DD + o1];
  float b1a = b1[o0], b1b = b1[o1];
  __syncthreads();
  float y0a = 0.f, y1a = 0.f, y2a = 0.f, y3a = 0.f;
  float y0b = 0.f, y1b = 0.f, y2b = 0.f, y3b = 0.f;
  int h0 = w * 128;
#pragma unroll 4
  for (int hh = h0; hh < h0 + 128; ++hh) {
    float4 xv = xb4[hh];
    float4 q = qv[hh];
    float c = csv[hh];
    float t0 = fmaf(c, cw4a, b1a);
    t0 = fmaf(xv.x, cw0a, t0);
    t0 = fmaf(xv.y, cw1a, t0);
    t0 = fmaf(xv.z, cw2a, t0);
    t0 = fmaf(xv.w, cw3a, t0);
    t0 = fmaxf(t0, 0.f);
    float t1 = fmaf(c, cw4b, b1b);
    t1 = fmaf(xv.x, cw0b, t1);
    t1 = fmaf(xv.y, cw1b, t1);
    t1 = fmaf(xv.z, cw2b, t1);
    t1 = fmaf(xv.w, cw3b, t1);
    t1 = fmaxf(t1, 0.f);
    y0a = fmaf(q.x, t0, y0a); y1a = fmaf(q.y, t0, y1a);
    y2a = fmaf(q.z, t0, y2a); y3a = fmaf(q.w, t0, y3a);
    y0b = fmaf(q.x, t1, y0b); y1b = fmaf(q.y, t1, y1b);
    y2b = fmaf(q.z, t1, y2b); y3b = fmaf(q.w, t1, y3b);
  }
  if (w == 0) {
    yL[o0] = y0a; yL[128 + o0] = y1a; yL[256 + o0] = y2a; yL[384 + o0] = y3a;
    yL[o1] = y0b; yL[128 + o1] = y1b; yL[256 + o1] = y2b; yL[384 + o1] = y3b;
  }
  __syncthreads();
  if (w == 1) {
    yL[o0] += y0a; yL[128 + o0] += y1a; yL[256 + o0] += y2a; yL[384 + o0] += y3a;
    yL[o1] += y0b; yL[128 + o1] += y1b; yL[256 + o1] += y2b; yL[384 + o1] += y3b;
  }
  __syncthreads();
  float* yp = ypar + ((size_t)qt * BB + b) * 512;
  for (int i = tid; i < 512; i += 128) yp[i] = yL[i];
}

// ---------------- epilogue GEMM: out0 = (sum_qt ypar) @ W2 + b2 + time ----------------
__global__ __launch_bounds__(256, 2) void k_out(const float* __restrict__ ypar,
                                                const __hip_bfloat16* __restrict__ w2sw,
                                                const float* __restrict__ b2,
                                                float* __restrict__ out) {
  __shared__ __align__(16) char Wr[32768];
  __shared__ __align__(16) char Gr[16384];
  int tid = threadIdx.x;
  int m0 = blockIdx.x * 64;
  {
    const uint4* ws = (const uint4*)w2sw;
    uint4* wd = (uint4*)Wr;
    for (int i = tid; i < 2048; i += 256) wd[i] = ws[i];
  }
#pragma unroll 4
  for (int it = 0; it < 16; ++it) {
    int pi = it * 256 + tid;
    int row = pi >> 6, kp = pi & 63;
    int base = (m0 + row) * 128 + 2 * kp;
    float s0 = 0.f, s1 = 0.f;
#pragma unroll
    for (int p = 0; p < 4; ++p) {
      s0 += ypar[(size_t)p * (BB * 512) + base];
      s1 += ypar[(size_t)p * (BB * 512) + base + 1];
    }
    union { __hip_bfloat16 h[2]; unsigned u; } pk;
    pk.h[0] = __float2bfloat16(s0);
    pk.h[1] = __float2bfloat16(s1);
    *(unsigned*)(Gr + row * 256 + (((kp >> 2) ^ (row & 7)) * 16) + (kp & 3) * 4) = pk.u;
  }
  int lane = tid & 63, w = tid >> 6;
  int colq = lane & 15, quad = lane >> 4;
  float bo[8];
#pragma unroll
  for (int jn = 0; jn < 8; ++jn) bo[jn] = b2[jn * 16 + colq];
  __syncthreads();

  f32x4 acc[8];
#pragma unroll
  for (int jn = 0; jn < 8; ++jn) acc[jn] = (f32x4){0.f, 0.f, 0.f, 0.f};
  int arow = w * 16 + colq;
#pragma unroll
  for (int kc = 0; kc < 4; ++kc) {
    bf16x8 af = *(const bf16x8*)(Gr + arow * 256 + (((kc * 4 + quad) ^ (arow & 7)) * 16));
#pragma unroll
    for (int jn = 0; jn < 8; ++jn) {
      int nr = jn * 16 + colq;
      bf16x8 bf = *(const bf16x8*)(Wr + nr * 256 + (((kc * 4 + quad) ^ (nr & 7)) * 16));
      acc[jn] = __builtin_amdgcn_mfma_f32_16x16x32_bf16(af, bf, acc[jn], 0, 0, 0);
    }
  }
#pragma unroll
  for (int reg = 0; reg < 4; ++reg) {
    int m = m0 + w * 16 + quad * 4 + reg;
    int b = m >> 2, g = m & 3;
    int n_ = b / TPP, tp = b % TPP;
    size_t rb = ((size_t)(n_ * TT + tp * 4 + g)) * DD;
#pragma unroll
    for (int jn = 0; jn < 8; ++jn) {
      int o = jn * 16 + colq;
      out[rb + o] = acc[jn][reg] + bo[jn] + out[(size_t)NOUT + rb + o];
    }
  }
}

extern "C" void kernel_launch(void* const* d_in, const int* in_sizes, int n_in,
                              void* d_out, int out_size, void* d_ws, size_t ws_size,
                              hipStream_t stream) {
  const float* x = (const float*)d_in[0];
  const int* xm = (const int*)d_in[1];
  const int* edges = (const int*)d_in[2];
  const int* node_split = (const int*)d_in[3];
  const float* hour_emb = (const float*)d_in[4];
  const float* wday_emb = (const float*)d_in[5];
  const float* timeconv_w = (const float*)d_in[6];
  const float* timeconv_b = (const float*)d_in[7];
  const float* tcw = (const float*)d_in[8];
  const float* tcb = (const float*)d_in[9];
  const float* W1 = (const float*)d_in[10];
  const float* b1 = (const float*)d_in[11];
  const float* W2 = (const float*)d_in[12];
  const float* b2 = (const float*)d_in[13];
  float* out = (float*)d_out;

  char* w = (char*)d_ws;
  int* degE = (int*)(w + 0);                 //    4096 B (memset)
  int* fill = (int*)(w + 4096);              //    4096 B (zeroed in k_setup)
  float* csum = (float*)(w + 8192);          //    4096 B (zeroed in k_setup)
  float* QT = (float*)(w + 12288);           //   16384 B (zeroed in k_setup)
  int* row_ptr = (int*)(w + 28672);          //    4352 B
  int* inv = (int*)(w + 33024);              //    4096 B
  int* csr_src = (int*)(w + 37120);          //   69632 B
  float* csr_coef = (float*)(w + 106752);    //   69632 B
  __hip_bfloat16* w2sw = (__hip_bfloat16*)(w + 176384);  // 32768 B
  float* CW = (float*)(w + 209152);          //    2560 B (pad to 4096)
  float* twT = (float*)(w + 213248);         //  262144 B
  __hip_bfloat16* Xall = (__hip_bfloat16*)(w + 475392);  // 3145728 B
  float* ypar = (float*)(w + 475392);        // overlay: Xall dead before k_red writes
  __hip_bfloat16* xbar = (__hip_bfloat16*)(w + 3621120); // 3145728 B (end ~6.77 MB)

  hipMemsetAsync(degE, 0, 4096, stream);
  k_setup<<<452, 256, 0, stream>>>(edges, degE, node_split, inv, timeconv_w, twT,
                                   (float*)(w + 4096), x, Xall, tcw, tcb, W1, CW, W2,
                                   w2sw);
  k_scatter<<<68, 256, 0, stream>>>(edges, degE, inv, fill, csr_src, csr_coef, csum,
                                    QT, row_ptr);
  k_spmm<<<HH + BB / 2, 256, 0, stream>>>(row_ptr, csr_src, csr_coef, Xall, xbar, xm,
                                          hour_emb, wday_emb, twT, timeconv_b, out);
  k_red<<<BB * 4, 128, 0, stream>>>(xbar, csum, QT, CW, b1, ypar);
  k_out<<<24, 256, 0, stream>>>(ypar, w2sw, b2, out);
}

// Round 3
// 141.305 us; speedup vs baseline: 1.1072x; 1.0171x over previous
//
#include <hip/hip_runtime.h>
#include <hip/hip_bf16.h>

#define NN 8
#define TT 192
#define HH 1024
#define DD 128
#define TPP 48
#define EE 16384
#define NEDGE (EE + HH)      // 17408
#define BB (NN * TPP)        // 384
#define NOUT (NN * TT * DD)  // 196608

typedef short bf16x8 __attribute__((ext_vector_type(8)));
typedef float f32x4 __attribute__((ext_vector_type(4)));

__device__ __forceinline__ float us2f(unsigned short u) {
  union { unsigned i; float f; } t;
  t.i = ((unsigned)u) << 16;
  return t.f;
}

__device__ __forceinline__ void acc6(float cf, unsigned u0, unsigned u1, unsigned u2,
                                     float& a0, float& a1, float& a2, float& a3,
                                     float& a4, float& a5) {
  union { unsigned i; float f; } lo, hi;
  lo.i = u0 << 16; hi.i = u0 & 0xffff0000u;
  a0 = fmaf(cf, lo.f, a0); a1 = fmaf(cf, hi.f, a1);
  lo.i = u1 << 16; hi.i = u1 & 0xffff0000u;
  a2 = fmaf(cf, lo.f, a2); a3 = fmaf(cf, hi.f, a3);
  lo.i = u2 << 16; hi.i = u2 & 0xffff0000u;
  a4 = fmaf(cf, lo.f, a4); a5 = fmaf(cf, hi.f, a5);
}

// ---------------- k_setup: everything that depends only on inputs ----------------
// blocks [0,384):   64x64 transpose tiles of x -> Xall bf16
// blocks [384,452): CW = Conv@W1 and W2 swizzle
// blocks [452,520): scatter (CSR build). deg + inv computed REDUNDANTLY per block
//                   in LDS, so no dependency on other blocks. Block 452 publishes
//                   row_ptr for k_spmm.
// blocks [520,712): time embedding (2 b's each, 192 blocks) -> out[NOUT..].
//                   Reads tw directly: twT[j*128+o] == tw[o*512+j], contiguous.
__global__ __launch_bounds__(256) void k_setup(
    const int* __restrict__ edges, const int* __restrict__ node_split,
    const float* __restrict__ x, __hip_bfloat16* __restrict__ Xall,
    const float* __restrict__ tcw, const float* __restrict__ tcb,
    const float* __restrict__ W1, float* __restrict__ CW,
    const float* __restrict__ W2, __hip_bfloat16* __restrict__ w2sw,
    int* __restrict__ fill, int* __restrict__ csr_src, float* __restrict__ csr_coef,
    float* __restrict__ csum, float* __restrict__ QT, int* __restrict__ row_ptr,
    const int* __restrict__ xm, const float* __restrict__ hour_emb,
    const float* __restrict__ wday_emb, const float* __restrict__ tw,
    float* __restrict__ out) {
  __shared__ float tile[64][65];
  __shared__ int hist[1024];
  __shared__ int rp2[1024];
  __shared__ int invS[1024];
  __shared__ int wsumS[4];
  int tid = threadIdx.x, bid = blockIdx.x;
  if (bid < 384) {
    // ---- transpose x (1536 x 1024 f32) -> Xall (1024 x 1536 bf16) ----
    int tt = bid % 24, st = bid / 24;  // t-tile, s-tile
    int t0 = tt * 64, s0 = st * 64;
    int sl = tid & 63, r4 = tid >> 6;
#pragma unroll 4
    for (int ii = 0; ii < 16; ++ii) {
      int tl = ii * 4 + r4;
      tile[tl][sl] = x[(size_t)(t0 + tl) * HH + s0 + sl];
    }
    __syncthreads();
#pragma unroll 4
    for (int ii = 0; ii < 16; ++ii) {
      int sl2 = ii * 4 + r4;
      Xall[(size_t)(s0 + sl2) * 1536 + t0 + sl] = __float2bfloat16(tile[sl][sl2]);
    }
  } else if (bid < 452) {
    // ---- CW = Conv@W1 (640) and W2 swizzle (16384) ----
    int ex = (bid - 384) * 256 + tid;
    if (ex < 640) {
      int j = ex >> 7, o = ex & 127;
      float acc = 0.f;
      if (j < 4)
        for (int d = 0; d < DD; ++d) acc = fmaf(tcw[d * 4 + j], W1[d * DD + o], acc);
      else
        for (int d = 0; d < DD; ++d) acc = fmaf(tcb[d], W1[d * DD + o], acc);
      CW[j * DD + o] = acc;
    }
    int ew = ex - 1024;
    if (ew >= 0 && ew < 16384) {
      int n = ew >> 7, k = ew & 127;
      int dstb = n * 256 + (((k >> 3) ^ (n & 7)) * 16) + (k & 7) * 2;
      w2sw[dstb >> 1] = __float2bfloat16(W2[k * DD + n]);
    }
  } else if (bid < 520) {
    // ---- scatter: per-block LDS degree histogram + inv + prefix scan + CSR ----
    int lane = tid & 63, wid = tid >> 6;
    for (int i = tid; i < 1024; i += 256) hist[i] = 1;  // +1 self loop
    for (int i = tid; i < 1024; i += 256) invS[node_split[i]] = i;
    __syncthreads();
    for (int e = tid; e < EE; e += 256) atomicAdd(&hist[edges[2 * e + 1]], 1);
    __syncthreads();
    int4 d4 = ((const int4*)hist)[tid];
    int l0 = d4.x, l1 = d4.y, l2 = d4.z, l3 = d4.w;
    int lsum = l0 + l1 + l2 + l3;
    int incl = lsum;
#pragma unroll
    for (int off = 1; off < 64; off <<= 1) {
      int u = __shfl_up(incl, off, 64);
      if (lane >= off) incl += u;
    }
    if (lane == 63) wsumS[wid] = incl;
    __syncthreads();
    int base = 0;
    if (wid > 0) base += wsumS[0];
    if (wid > 1) base += wsumS[1];
    if (wid > 2) base += wsumS[2];
    int excl = base + incl - lsum;
    rp2[4 * tid] = excl;
    rp2[4 * tid + 1] = excl + l0;
    rp2[4 * tid + 2] = excl + l0 + l1;
    rp2[4 * tid + 3] = excl + l0 + l1 + l2;
    __syncthreads();
    if (bid == 452) {
      for (int i = tid; i < 1024; i += 256) row_ptr[i] = rp2[i];
      if (tid == 0) row_ptr[1024] = NEDGE;
    }
    int e = (bid - 452) * 256 + tid;  // [0, 17408)
    int s, dt;
    if (e < EE) {
      int2 ed = ((const int2*)edges)[e];
      s = ed.x; dt = ed.y;
    } else {
      s = dt = e - EE;
    }
    float cf = rsqrtf((float)hist[s] * (float)hist[dt]);
    int pos = atomicAdd(&fill[dt], 1);
    int at = rp2[dt] + pos;
    csr_src[at] = s;
    csr_coef[at] = cf;
    atomicAdd(&csum[dt], cf);
    int g = invS[dt] >> 8;
    atomicAdd(&QT[s * 4 + g], cf * (1.0f / 256.0f));
  } else {
    // ---- time embedding for 2 b's per block (192 blocks cover b in [0,384)) ----
    __shared__ float sL[2][512];
    int bb = bid - 520;
    int half = tid >> 7, o = tid & 127;
    int b = bb * 2 + half;
    int n = b / TPP, tp = b % TPP;
    for (int k = 0; k < 4; ++k) {
      int t = tp * 4 + k;
      int wd = xm[(n * TT + t) * 2 + 0];
      int hr = xm[(n * TT + t) * 2 + 1];
      sL[half][o * 4 + k] = hour_emb[hr * DD + o] + wday_emb[wd * DD + o];
    }
    __syncthreads();
    const float* twr = tw + (size_t)o * 512;  // tw is [128][512]: W[o][c*4+k]
    float a0 = tcb[o], a1 = 0.f, a2 = 0.f, a3 = 0.f;
    for (int j = 0; j < 512; j += 4) {
      a0 = fmaf(sL[half][j + 0], twr[j + 0], a0);
      a1 = fmaf(sL[half][j + 1], twr[j + 1], a1);
      a2 = fmaf(sL[half][j + 2], twr[j + 2], a2);
      a3 = fmaf(sL[half][j + 3], twr[j + 3], a3);
    }
    float acc = (a0 + a1) + (a2 + a3);
    size_t base = (size_t)NOUT + ((size_t)n * TT + tp * 4) * DD + o;
    out[base] = acc;
    out[base + DD] = acc;
    out[base + 2 * DD] = acc;
    out[base + 3 * DD] = acc;
  }
}

// ---------------- SpMM: xbar = Ahat @ Xall (row per block) ----------------
__global__ __launch_bounds__(256) void k_spmm(
    const int* __restrict__ row_ptr, const int* __restrict__ csr_src,
    const float* __restrict__ csr_coef, const __hip_bfloat16* __restrict__ Xall,
    __hip_bfloat16* __restrict__ xbar) {
  __shared__ int sS[256];
  __shared__ float sC[256];
  int tid = threadIdx.x, h = blockIdx.x;
  int j0 = row_ptr[h], j1 = row_ptr[h + 1];
  int cnt = j1 - j0;
  int cs = cnt < 256 ? cnt : 256;
  if (tid < cs) { sS[tid] = csr_src[j0 + tid]; sC[tid] = csr_coef[j0 + tid]; }
  __syncthreads();
  float a0 = 0.f, a1 = 0.f, a2 = 0.f, a3 = 0.f, a4 = 0.f, a5 = 0.f;
  int j = 0;
  for (; j + 4 <= cs; j += 4) {
    const unsigned* x0 = (const unsigned*)(Xall + (size_t)sS[j] * 1536);
    const unsigned* x1 = (const unsigned*)(Xall + (size_t)sS[j + 1] * 1536);
    const unsigned* x2 = (const unsigned*)(Xall + (size_t)sS[j + 2] * 1536);
    const unsigned* x3 = (const unsigned*)(Xall + (size_t)sS[j + 3] * 1536);
    unsigned u00 = x0[tid], u01 = x0[tid + 256], u02 = x0[tid + 512];
    unsigned u10 = x1[tid], u11 = x1[tid + 256], u12 = x1[tid + 512];
    unsigned u20 = x2[tid], u21 = x2[tid + 256], u22 = x2[tid + 512];
    unsigned u30 = x3[tid], u31 = x3[tid + 256], u32 = x3[tid + 512];
    float c0 = sC[j], c1 = sC[j + 1], c2 = sC[j + 2], c3 = sC[j + 3];
    acc6(c0, u00, u01, u02, a0, a1, a2, a3, a4, a5);
    acc6(c1, u10, u11, u12, a0, a1, a2, a3, a4, a5);
    acc6(c2, u20, u21, u22, a0, a1, a2, a3, a4, a5);
    acc6(c3, u30, u31, u32, a0, a1, a2, a3, a4, a5);
  }
  for (; j < cs; ++j) {
    const unsigned* xr = (const unsigned*)(Xall + (size_t)sS[j] * 1536);
    unsigned u0 = xr[tid], u1 = xr[tid + 256], u2 = xr[tid + 512];
    acc6(sC[j], u0, u1, u2, a0, a1, a2, a3, a4, a5);
  }
  for (; j < cnt; ++j) {  // safety: degree > 256 (never expected)
    int s = csr_src[j0 + j];
    float cf = csr_coef[j0 + j];
    const unsigned* xr = (const unsigned*)(Xall + (size_t)s * 1536);
    unsigned u0 = xr[tid], u1 = xr[tid + 256], u2 = xr[tid + 512];
    acc6(cf, u0, u1, u2, a0, a1, a2, a3, a4, a5);
  }
  unsigned* xw = (unsigned*)(xbar + (size_t)h * 1536);
  union { __hip_bfloat16 h2[2]; unsigned u; } pk;
  pk.h2[0] = __float2bfloat16(a0); pk.h2[1] = __float2bfloat16(a1);
  xw[tid] = pk.u;
  pk.h2[0] = __float2bfloat16(a2); pk.h2[1] = __float2bfloat16(a3);
  xw[tid + 256] = pk.u;
  pk.h2[0] = __float2bfloat16(a4); pk.h2[1] = __float2bfloat16(a5);
  xw[tid + 512] = pk.u;
}

// ---------------- k_red: y[b,g,o] = sum_h QT[h,g]*relu(xbar5[b,h,:]@CW + b1) ----------------
__global__ __launch_bounds__(128) void k_red(const __hip_bfloat16* __restrict__ xbar,
                                             const float* __restrict__ csum,
                                             const float* __restrict__ QT,
                                             const float* __restrict__ CW,
                                             const float* __restrict__ b1,
                                             float* __restrict__ ypar) {
  __shared__ float4 xb4[256];
  __shared__ float4 qv[256];
  __shared__ float csv[256];
  __shared__ float yL[512];
  int tid = threadIdx.x, bid = blockIdx.x;
  int b = bid >> 2, qt = bid & 3;
  for (int r = tid; r < 256; r += 128) {
    int h = qt * 256 + r;
    ushort4 us = *(const ushort4*)(xbar + (size_t)h * 1536 + b * 4);
    xb4[r] = make_float4(us2f(us.x), us2f(us.y), us2f(us.z), us2f(us.w));
    qv[r] = *(const float4*)(QT + h * 4);
    csv[r] = csum[h];
  }
  int lane = tid & 63, w = tid >> 6;
  int o0 = lane, o1 = lane + 64;
  float cw0a = CW[o0], cw1a = CW[DD + o0], cw2a = CW[2 * DD + o0];
  float cw3a = CW[3 * DD + o0], cw4a = CW[4 * DD + o0];
  float cw0b = CW[o1], cw1b = CW[DD + o1], cw2b = CW[2 * DD + o1];
  float cw3b = CW[3 * DD + o1], cw4b = CW[4 * DD + o1];
  float b1a = b1[o0], b1b = b1[o1];
  __syncthreads();
  float y0a = 0.f, y1a = 0.f, y2a = 0.f, y3a = 0.f;
  float y0b = 0.f, y1b = 0.f, y2b = 0.f, y3b = 0.f;
  int h0 = w * 128;
#pragma unroll 4
  for (int hh = h0; hh < h0 + 128; ++hh) {
    float4 xv = xb4[hh];
    float4 q = qv[hh];
    float c = csv[hh];
    float t0 = fmaf(c, cw4a, b1a);
    t0 = fmaf(xv.x, cw0a, t0);
    t0 = fmaf(xv.y, cw1a, t0);
    t0 = fmaf(xv.z, cw2a, t0);
    t0 = fmaf(xv.w, cw3a, t0);
    t0 = fmaxf(t0, 0.f);
    float t1 = fmaf(c, cw4b, b1b);
    t1 = fmaf(xv.x, cw0b, t1);
    t1 = fmaf(xv.y, cw1b, t1);
    t1 = fmaf(xv.z, cw2b, t1);
    t1 = fmaf(xv.w, cw3b, t1);
    t1 = fmaxf(t1, 0.f);
    y0a = fmaf(q.x, t0, y0a); y1a = fmaf(q.y, t0, y1a);
    y2a = fmaf(q.z, t0, y2a); y3a = fmaf(q.w, t0, y3a);
    y0b = fmaf(q.x, t1, y0b); y1b = fmaf(q.y, t1, y1b);
    y2b = fmaf(q.z, t1, y2b); y3b = fmaf(q.w, t1, y3b);
  }
  if (w == 0) {
    yL[o0] = y0a; yL[128 + o0] = y1a; yL[256 + o0] = y2a; yL[384 + o0] = y3a;
    yL[o1] = y0b; yL[128 + o1] = y1b; yL[256 + o1] = y2b; yL[384 + o1] = y3b;
  }
  __syncthreads();
  if (w == 1) {
    yL[o0] += y0a; yL[128 + o0] += y1a; yL[256 + o0] += y2a; yL[384 + o0] += y3a;
    yL[o1] += y0b; yL[128 + o1] += y1b; yL[256 + o1] += y2b; yL[384 + o1] += y3b;
  }
  __syncthreads();
  float* yp = ypar + ((size_t)qt * BB + b) * 512;
  for (int i = tid; i < 512; i += 128) yp[i] = yL[i];
}

// ---------------- epilogue GEMM: out0 = (sum_qt ypar) @ W2 + b2 + time ----------------
__global__ __launch_bounds__(256, 2) void k_out(const float* __restrict__ ypar,
                                                const __hip_bfloat16* __restrict__ w2sw,
                                                const float* __restrict__ b2,
                                                float* __restrict__ out) {
  __shared__ __align__(16) char Wr[32768];
  __shared__ __align__(16) char Gr[16384];
  int tid = threadIdx.x;
  int m0 = blockIdx.x * 64;
  {
    const uint4* ws = (const uint4*)w2sw;
    uint4* wd = (uint4*)Wr;
    for (int i = tid; i < 2048; i += 256) wd[i] = ws[i];
  }
#pragma unroll 4
  for (int it = 0; it < 16; ++it) {
    int pi = it * 256 + tid;
    int row = pi >> 6, kp = pi & 63;
    int base = (m0 + row) * 128 + 2 * kp;
    float s0 = 0.f, s1 = 0.f;
#pragma unroll
    for (int p = 0; p < 4; ++p) {
      s0 += ypar[(size_t)p * (BB * 512) + base];
      s1 += ypar[(size_t)p * (BB * 512) + base + 1];
    }
    union { __hip_bfloat16 h[2]; unsigned u; } pk;
    pk.h[0] = __float2bfloat16(s0);
    pk.h[1] = __float2bfloat16(s1);
    *(unsigned*)(Gr + row * 256 + (((kp >> 2) ^ (row & 7)) * 16) + (kp & 3) * 4) = pk.u;
  }
  int lane = tid & 63, w = tid >> 6;
  int colq = lane & 15, quad = lane >> 4;
  float bo[8];
#pragma unroll
  for (int jn = 0; jn < 8; ++jn) bo[jn] = b2[jn * 16 + colq];
  __syncthreads();

  f32x4 acc[8];
#pragma unroll
  for (int jn = 0; jn < 8; ++jn) acc[jn] = (f32x4){0.f, 0.f, 0.f, 0.f};
  int arow = w * 16 + colq;
#pragma unroll
  for (int kc = 0; kc < 4; ++kc) {
    bf16x8 af = *(const bf16x8*)(Gr + arow * 256 + (((kc * 4 + quad) ^ (arow & 7)) * 16));
#pragma unroll
    for (int jn = 0; jn < 8; ++jn) {
      int nr = jn * 16 + colq;
      bf16x8 bf = *(const bf16x8*)(Wr + nr * 256 + (((kc * 4 + quad) ^ (nr & 7)) * 16));
      acc[jn] = __builtin_amdgcn_mfma_f32_16x16x32_bf16(af, bf, acc[jn], 0, 0, 0);
    }
  }
#pragma unroll
  for (int reg = 0; reg < 4; ++reg) {
    int m = m0 + w * 16 + quad * 4 + reg;
    int b = m >> 2, g = m & 3;
    int n_ = b / TPP, tp = b % TPP;
    size_t rb = ((size_t)(n_ * TT + tp * 4 + g)) * DD;
#pragma unroll
    for (int jn = 0; jn < 8; ++jn) {
      int o = jn * 16 + colq;
      out[rb + o] = acc[jn][reg] + bo[jn] + out[(size_t)NOUT + rb + o];
    }
  }
}

extern "C" void kernel_launch(void* const* d_in, const int* in_sizes, int n_in,
                              void* d_out, int out_size, void* d_ws, size_t ws_size,
                              hipStream_t stream) {
  const float* x = (const float*)d_in[0];
  const int* xm = (const int*)d_in[1];
  const int* edges = (const int*)d_in[2];
  const int* node_split = (const int*)d_in[3];
  const float* hour_emb = (const float*)d_in[4];
  const float* wday_emb = (const float*)d_in[5];
  const float* timeconv_w = (const float*)d_in[6];
  const float* timeconv_b = (const float*)d_in[7];
  const float* tcw = (const float*)d_in[8];
  const float* tcb = (const float*)d_in[9];
  const float* W1 = (const float*)d_in[10];
  const float* b1 = (const float*)d_in[11];
  const float* W2 = (const float*)d_in[12];
  const float* b2 = (const float*)d_in[13];
  float* out = (float*)d_out;

  char* w = (char*)d_ws;
  int* fill = (int*)(w + 4096);              //    4096 B (memset)
  float* csum = (float*)(w + 8192);          //    4096 B (memset)
  float* QT = (float*)(w + 12288);           //   16384 B (memset)
  int* row_ptr = (int*)(w + 28672);          //    4352 B
  int* csr_src = (int*)(w + 37120);          //   69632 B
  float* csr_coef = (float*)(w + 106752);    //   69632 B
  __hip_bfloat16* w2sw = (__hip_bfloat16*)(w + 176384);  // 32768 B
  float* CW = (float*)(w + 209152);          //    2560 B
  __hip_bfloat16* Xall = (__hip_bfloat16*)(w + 475392);  // 3145728 B
  float* ypar = (float*)(w + 475392);        // overlay: Xall dead before k_red writes
  __hip_bfloat16* xbar = (__hip_bfloat16*)(w + 3621120); // 3145728 B (end ~6.77 MB)

  hipMemsetAsync(w + 4096, 0, 24576, stream);  // fill | csum | QT
  k_setup<<<712, 256, 0, stream>>>(edges, node_split, x, Xall, tcw, tcb, W1, CW, W2,
                                   w2sw, fill, csr_src, csr_coef, csum, QT, row_ptr,
                                   xm, hour_emb, wday_emb, timeconv_w, out);
  k_spmm<<<HH, 256, 0, stream>>>(row_ptr, csr_src, csr_coef, Xall, xbar);
  k_red<<<BB * 4, 128, 0, stream>>>(xbar, csum, QT, CW, b1, ypar);
  k_out<<<24, 256, 0, stream>>>(ypar, w2sw, b2, out);
}